// Round 11
// baseline (373.093 us; speedup 1.0000x reference)
//
#include <hip/hip_runtime.h>

#define N_NODES 50000
#define N_EDGES 600000
#define DIM 128
#define N_LAYERS 4
#define N_GRAPHS 64
#define NEG_SLOPE 0.01f
#define NB_SCAN ((N_NODES + 255) / 256)   // 196
#define NB_CNT ((N_EDGES + 255) / 256)    // 2344
#define NC_CONV (N_NODES * DIM / 8 / 256) // 3125
#define NB_PACK 64
#define RS 264  // LDS row stride in bf16 elems: 256 data + 8 pad (16B mult)

typedef __attribute__((ext_vector_type(8))) short short8;
typedef __attribute__((ext_vector_type(16))) float floatx16;
typedef __attribute__((ext_vector_type(2))) float float2v;

__device__ __forceinline__ unsigned short f2bf(float f) {
    union { float f; unsigned u; } c; c.f = f;
    unsigned u = c.u;
    unsigned r = (u + 0x7FFFu + ((u >> 16) & 1u)) >> 16;
    return (unsigned short)r;
}
__device__ __forceinline__ float bfraw2f(unsigned short b) {
    union { unsigned u; float f; } c; c.u = ((unsigned)b) << 16;
    return c.f;
}
__device__ __forceinline__ unsigned f2fp8(float v) {  // 1 byte, e4m3 OCP
    return __builtin_amdgcn_cvt_pk_fp8_f32(v, v, 0, false) & 0xFFu;
}
// dequant 4 fp8 bytes of w into a[0..3]
__device__ __forceinline__ void dq_add(unsigned w, float* a) {
    float2v f0 = __builtin_amdgcn_cvt_pk_f32_fp8(w, false);
    float2v f1 = __builtin_amdgcn_cvt_pk_f32_fp8(w, true);
    a[0] += f0.x; a[1] += f0.y; a[2] += f1.x; a[3] += f1.y;
}

// ---------------- zero deg+fill (adjacent) and pooled ----------------
__global__ void zero2(int* a, int na, int* b, int nb) {
    int i = blockIdx.x * blockDim.x + threadIdx.x;
    if (i < na) a[i] = 0;
    else if (i < na + nb) b[i - na] = 0;
}

// ---------------- merged: convert_x (bf16 + fp8) | pack_w | count_deg ----------
__global__ void preprocess(const float4* __restrict__ x, uint4* __restrict__ xb,
                           uint2* __restrict__ xq8,
                           const float* __restrict__ Wl, const float* __restrict__ Wr,
                           ushort* __restrict__ wpk,
                           const int* __restrict__ edst, int* __restrict__ deg) {
    int b = blockIdx.x;
    if (b < NC_CONV) {
        int i = b * 256 + threadIdx.x;  // chunk of 8 floats
        float4 a = x[i * 2], c = x[i * 2 + 1];
        uint4 o;
        o.x = ((unsigned)f2bf(a.y) << 16) | f2bf(a.x);
        o.y = ((unsigned)f2bf(a.w) << 16) | f2bf(a.z);
        o.z = ((unsigned)f2bf(c.y) << 16) | f2bf(c.x);
        o.w = ((unsigned)f2bf(c.w) << 16) | f2bf(c.z);
        xb[i] = o;
        unsigned lo = __builtin_amdgcn_cvt_pk_fp8_f32(a.x, a.y, 0, false);
        lo = __builtin_amdgcn_cvt_pk_fp8_f32(a.z, a.w, lo, true);
        unsigned hi = __builtin_amdgcn_cvt_pk_fp8_f32(c.x, c.y, 0, false);
        hi = __builtin_amdgcn_cvt_pk_fp8_f32(c.z, c.w, hi, true);
        xq8[i] = make_uint2(lo, hi);
    } else if (b < NC_CONV + NB_PACK) {
        // pack weights into MFMA B-fragment order.
        int u = (b - NC_CONV) * 4 + (threadIdx.x >> 6);
        int l = threadIdx.x & 63;
        int layer = u >> 6, m = (u >> 5) & 1, s = (u >> 2) & 7, tt = u & 3;
        const float* W = ((m == 0) ? Wl : Wr) + (size_t)layer * DIM * DIM;
        int n = tt * 32 + (l & 31);
        int kb = s * 16 + (l >> 5) * 8;
        size_t off = ((size_t)u * 64 + l) * 8;
        for (int j = 0; j < 8; j++)
            wpk[off + j] = f2bf(W[n * DIM + kb + j]);
    } else {
        int e = (b - NC_CONV - NB_PACK) * 256 + threadIdx.x;
        if (e < N_EDGES) atomicAdd(&deg[edst[e]], 1);
    }
}

// ---------------- 3-pass exclusive scan of deg -> rp ----------------
__global__ void scan_pass1(const int* __restrict__ deg, int* __restrict__ bsum) {
    int i = blockIdx.x * 256 + threadIdx.x;
    int v = (i < N_NODES) ? deg[i] : 0;
    for (int off = 32; off > 0; off >>= 1) v += __shfl_down(v, off, 64);
    __shared__ int ws[4];
    int lane = threadIdx.x & 63, w = threadIdx.x >> 6;
    if (lane == 0) ws[w] = v;
    __syncthreads();
    if (threadIdx.x == 0) bsum[blockIdx.x] = ws[0] + ws[1] + ws[2] + ws[3];
}

__global__ void scan_pass2(int* __restrict__ bsum) {
    __shared__ int sm[256];
    int t = threadIdx.x;
    int v = (t < NB_SCAN) ? bsum[t] : 0;
    sm[t] = v;
    __syncthreads();
    for (int off = 1; off < 256; off <<= 1) {
        int u = (t >= off) ? sm[t - off] : 0;
        __syncthreads();
        sm[t] += u;
        __syncthreads();
    }
    if (t < NB_SCAN) bsum[t] = sm[t] - v;
}

__global__ void scan_pass3(const int* __restrict__ deg, const int* __restrict__ bsum,
                           int* __restrict__ rp) {
    int i = blockIdx.x * 256 + threadIdx.x;
    int v = (i < N_NODES) ? deg[i] : 0;
    int lane = threadIdx.x & 63, w = threadIdx.x >> 6;
    int s = v;
    for (int off = 1; off < 64; off <<= 1) {
        int t = __shfl_up(s, off, 64);
        if (lane >= off) s += t;
    }
    __shared__ int ws[4];
    if (lane == 63) ws[w] = s;
    __syncthreads();
    int wo = 0;
    for (int k = 0; k < 4; k++) wo += (k < w) ? ws[k] : 0;
    int incl = s + wo + bsum[blockIdx.x];
    if (i < N_NODES) rp[i + 1] = incl;
    if (i == 0) rp[0] = 0;
}

// ---------------- merged: fill_csr | graph_start ----------------
__global__ void fill_gstart(const int* __restrict__ src, const int* __restrict__ dst,
                            const int* __restrict__ rp, int* __restrict__ fill,
                            int* __restrict__ csr,
                            const int* __restrict__ batch, int* __restrict__ gstart) {
    int b = blockIdx.x;
    if (b < NB_CNT) {
        int e = b * 256 + threadIdx.x;
        if (e >= N_EDGES) return;
        int d = dst[e];
        int pos = atomicAdd(&fill[d], 1);
        csr[rp[d] + pos] = src[e];
    } else {
        int i = (b - NB_CNT) * 256 + threadIdx.x;
        if (i >= N_NODES) return;
        int g0 = batch[i];
        if (i == 0) {
            for (int g = 0; g <= g0; g++) gstart[g] = 0;
        } else {
            int p = batch[i - 1];
            for (int g = p + 1; g <= g0; g++) gstart[g] = i;
        }
        if (i == N_NODES - 1) {
            for (int g = g0 + 1; g <= N_GRAPHS; g++) gstart[g] = N_NODES;
        }
    }
}

// ---------------- aggregation: fp8 gather (2 lines/edge), wave per node ----------
// Row = 128 fp8 bytes = 8 uint4. lane = eg*8 + ll: 8 edges per wave-load, lane
// covers dims [ll*16, ll*16+16). Unroll 2 -> 2 loads (32 lines) in flight/wave.
// Accumulate f32 via v_cvt_pk_f32_fp8; output agg row in bf16 for the MFMA stage.
__global__ __launch_bounds__(256) void agg_mean_fp8(const uint4* __restrict__ x8,
                                                    const int* __restrict__ rp,
                                                    const int* __restrict__ csr,
                                                    uint4* __restrict__ agg16B) {
    int wv = threadIdx.x >> 6, lane = threadIdx.x & 63;
    int node = blockIdx.x * 4 + wv;
    if (node >= N_NODES) return;
    int s = rp[node], e = rp[node + 1];
    int ll = lane & 7, eg = lane >> 3;
    float acc[16];
#pragma unroll
    for (int k = 0; k < 16; k++) acc[k] = 0.f;

    for (int base = s; base < e; base += 64) {
        int cnt = min(64, e - base);
        unsigned myidx = (base + lane < e) ? (unsigned)csr[base + lane] : 0u;
        for (int j = 0; j < cnt; j += 16) {
            int sel0 = j + eg, sel1 = j + 8 + eg;
            unsigned i0 = __shfl(myidx, sel0, 64);
            unsigned i1 = __shfl(myidx, sel1, 64);
            uint4 v0 = make_uint4(0u, 0u, 0u, 0u);
            uint4 v1 = make_uint4(0u, 0u, 0u, 0u);
            if (sel0 < cnt) v0 = x8[(size_t)i0 * 8 + ll];
            if (sel1 < cnt) v1 = x8[(size_t)i1 * 8 + ll];
            dq_add(v0.x, acc + 0); dq_add(v0.y, acc + 4);
            dq_add(v0.z, acc + 8); dq_add(v0.w, acc + 12);
            dq_add(v1.x, acc + 0); dq_add(v1.y, acc + 4);
            dq_add(v1.z, acc + 8); dq_add(v1.w, acc + 12);
        }
    }
    // reduce across the 8 edge-groups (lane bits 3,4,5)
#pragma unroll
    for (int k = 0; k < 16; k++) {
        acc[k] += __shfl_xor(acc[k], 8, 64);
        acc[k] += __shfl_xor(acc[k], 16, 64);
        acc[k] += __shfl_xor(acc[k], 32, 64);
    }
    if (eg == 0) {
        float inv = 1.0f / (float)max(e - s, 1);
        uint4 o0, o1;
        o0.x = ((unsigned)f2bf(acc[1] * inv) << 16) | f2bf(acc[0] * inv);
        o0.y = ((unsigned)f2bf(acc[3] * inv) << 16) | f2bf(acc[2] * inv);
        o0.z = ((unsigned)f2bf(acc[5] * inv) << 16) | f2bf(acc[4] * inv);
        o0.w = ((unsigned)f2bf(acc[7] * inv) << 16) | f2bf(acc[6] * inv);
        o1.x = ((unsigned)f2bf(acc[9] * inv) << 16) | f2bf(acc[8] * inv);
        o1.y = ((unsigned)f2bf(acc[11] * inv) << 16) | f2bf(acc[10] * inv);
        o1.z = ((unsigned)f2bf(acc[13] * inv) << 16) | f2bf(acc[12] * inv);
        o1.w = ((unsigned)f2bf(acc[15] * inv) << 16) | f2bf(acc[14] * inv);
        agg16B[(size_t)node * 16 + ll * 2] = o0;
        agg16B[(size_t)node * 16 + ll * 2 + 1] = o1;
    }
}

// ---------------- fused dual-GEMM layer, MFMA bf16, 64-node blocks ----------------
// Epilogue dual-stores bf16 (xout) + fp8 (xq8, next layer's gather payload).
__global__ __launch_bounds__(256, 4) void fused_layer_mfma(const ushort* __restrict__ agg,
                                                           const ushort* __restrict__ xin,
                                                           ushort* __restrict__ xout,
                                                           unsigned char* __restrict__ xq8,
                                                           const ushort* __restrict__ wpk,
                                                           const float* __restrict__ bias,
                                                           int residual) {
    __shared__ ushort sA[64 * RS];  // row r: [agg(128) | x(128) | pad(8)]
    int t = threadIdx.x;
    int node0 = blockIdx.x * 64;

    const uint4* aggv = (const uint4*)(agg + (size_t)node0 * DIM);
    const uint4* xv   = (const uint4*)(xin + (size_t)node0 * DIM);
    for (int i = t; i < 64 * 32; i += 256) {
        int r = i >> 5, c = i & 31;
        uint4 val = make_uint4(0u, 0u, 0u, 0u);
        if (node0 + r < N_NODES)
            val = (c < 16) ? aggv[r * 16 + c] : xv[r * 16 + (c - 16)];
        *(uint4*)&sA[r * RS + c * 8] = val;
    }
    __syncthreads();

    int w = t >> 6, l = t & 63;
    int m0 = (w >> 1) * 32;
    int th = w & 1;  // output half
    const ushort* arow = &sA[(m0 + (l & 31)) * RS];
    int khalf = (l >> 5) * 8;

    floatx16 acc0, acc1;
    for (int ii = 0; ii < 16; ii++) acc0[ii] = acc1[ii] = 0.f;

    const ushort* wl8 = wpk + (size_t)l * 8 + (size_t)(2 * th) * 512;
#pragma unroll
    for (int s2 = 0; s2 < 16; s2++) {
        int m = s2 >> 3, s = s2 & 7;
        short8 a = *(const short8*)(arow + m * 128 + s * 16 + khalf);
        size_t fb = (size_t)((m * 8 + s) * 4) * 512;
        short8 b0 = *(const short8*)(wl8 + fb);
        short8 b1 = *(const short8*)(wl8 + fb + 512);
        acc0 = __builtin_amdgcn_mfma_f32_32x32x16_bf16(a, b0, acc0, 0, 0, 0);
        acc1 = __builtin_amdgcn_mfma_f32_32x32x16_bf16(a, b1, acc1, 0, 0, 0);
    }

    int col = l & 31;
    int rbase = 4 * (l >> 5);
    floatx16 accs[2] = {acc0, acc1};
    for (int ti = 0; ti < 2; ti++) {
        int n = (2 * th + ti) * 32 + col;
        float bv = bias[n];
#pragma unroll
        for (int r = 0; r < 16; r++) {
            int row = (r & 3) + 8 * (r >> 2) + rbase;
            int gm = m0 + row;
            int gn = node0 + gm;
            if (gn >= N_NODES) continue;
            float v = accs[ti][r] + bv;
            v = (v >= 0.f) ? v : NEG_SLOPE * v;
            if (residual) v += bfraw2f(sA[gm * RS + 128 + n]);
            xout[(size_t)gn * DIM + n] = f2bf(v);
            xq8[(size_t)gn * DIM + n] = (unsigned char)f2fp8(v);
        }
    }
}

// ---------------- global mean pool, parallel segment-sum ----------------
__global__ __launch_bounds__(128) void pool_partial(const ushort* __restrict__ xb,
                                                    const int* __restrict__ batch,
                                                    float* __restrict__ pooled) {
    int nb = blockIdx.x * 128;
    int ne = min(nb + 128, N_NODES);
    int d = threadIdx.x;
    int gcur = batch[nb];
    float acc = 0.f;
    for (int n = nb; n < ne; n++) {
        int g = batch[n];
        if (g != gcur) {
            atomicAdd(&pooled[gcur * DIM + d], acc);
            acc = 0.f;
            gcur = g;
        }
        acc += bfraw2f(xb[(size_t)n * DIM + d]);
    }
    atomicAdd(&pooled[gcur * DIM + d], acc);
}

__global__ void pool_final(const float* __restrict__ pooled,
                           const int* __restrict__ gstart,
                           float* __restrict__ out) {
    int i = blockIdx.x * blockDim.x + threadIdx.x;
    if (i >= N_GRAPHS * DIM) return;
    int g = i >> 7;
    int cnt = gstart[g + 1] - gstart[g];
    out[i] = pooled[i] / (float)max(cnt, 1);
}

// ---------------- launch ----------------

extern "C" void kernel_launch(void* const* d_in, const int* in_sizes, int n_in,
                              void* d_out, int out_size, void* d_ws, size_t ws_size,
                              hipStream_t stream) {
    const float* x     = (const float*)d_in[0];
    const int*   ei    = (const int*)d_in[1];
    const int*   batch = (const int*)d_in[2];
    const float* Wl    = (const float*)d_in[3];
    const float* bl    = (const float*)d_in[4];
    const float* Wr    = (const float*)d_in[5];
    float* out = (float*)d_out;

    const int* esrc = ei;
    const int* edst = ei + N_EDGES;

    // workspace layout
    ushort* xb0  = (ushort*)d_ws;                         // [N,128] bf16
    ushort* xbuf = xb0 + (size_t)N_NODES * DIM;           // [N,128] bf16
    ushort* agg  = xbuf + (size_t)N_NODES * DIM;          // [N,128] bf16
    ushort* wpk  = agg + (size_t)N_NODES * DIM;           // [4][2][128*128] bf16
    unsigned char* xq8 = (unsigned char*)(wpk + (size_t)N_LAYERS * 2 * DIM * DIM); // [N,128] fp8
    int* deg    = (int*)(xq8 + (size_t)N_NODES * DIM);
    int* fill   = deg + N_NODES;
    int* csr    = fill + N_NODES;
    int* rp     = csr + N_EDGES;
    int* gstart = rp + (N_NODES + 1);
    int* bsum   = gstart + (N_GRAPHS + 1);
    float* pooled = (float*)(bsum + NB_SCAN);             // [G,128] fp32

    // 1. zero deg+fill (adjacent, 2N) and pooled (G*D)
    zero2<<<(2 * N_NODES + N_GRAPHS * DIM + 255) / 256, 256, 0, stream>>>(
        deg, 2 * N_NODES, (int*)pooled, N_GRAPHS * DIM);

    // 2. convert (bf16+fp8) | pack | count (one grid)
    preprocess<<<NC_CONV + NB_PACK + NB_CNT, 256, 0, stream>>>(
        (const float4*)x, (uint4*)xb0, (uint2*)xq8, Wl, Wr, wpk, edst, deg);

    // 3. scan
    scan_pass1<<<NB_SCAN, 256, 0, stream>>>(deg, bsum);
    scan_pass2<<<1, 256, 0, stream>>>(bsum);
    scan_pass3<<<NB_SCAN, 256, 0, stream>>>(deg, bsum, rp);

    // 4. fill csr | graph segment starts
    fill_gstart<<<NB_CNT + NB_SCAN, 256, 0, stream>>>(esrc, edst, rp, fill, csr,
                                                      batch, gstart);

    // 5. layers: fp8 gather-agg + bf16 MFMA (agg(l) reads xq8 before gemm(l)
    //    overwrites it -> stream order makes single xq8 buffer safe)
    int agg_blocks = (N_NODES + 3) / 4;
    int gemm_blocks = (N_NODES + 63) / 64;
    for (int l = 0; l < N_LAYERS; l++) {
        const ushort* xin = (l == 0) ? xb0 : xbuf;
        agg_mean_fp8<<<agg_blocks, 256, 0, stream>>>((const uint4*)xq8, rp, csr,
                                                     (uint4*)agg);
        fused_layer_mfma<<<gemm_blocks, 256, 0, stream>>>(
            agg, xin, xbuf, xq8, wpk + (size_t)l * 2 * DIM * DIM,
            bl + (size_t)l * DIM, (l >= 2) ? 1 : 0);
    }

    // 6. pool
    pool_partial<<<(N_NODES + 127) / 128, 128, 0, stream>>>(xbuf, batch, pooled);
    pool_final<<<(N_GRAPHS * DIM + 255) / 256, 256, 0, stream>>>(pooled, gstart, out);
}

// Round 12
// 336.973 us; speedup vs baseline: 1.1072x; 1.1072x over previous
//
#include <hip/hip_runtime.h>

#define N_NODES 50000
#define N_EDGES 600000
#define DIM 128
#define N_LAYERS 4
#define N_GRAPHS 64
#define NEG_SLOPE 0.01f
#define NB_SCAN ((N_NODES + 255) / 256)   // 196
#define NB_CNT ((N_EDGES + 255) / 256)    // 2344
#define NC_CONV (N_NODES * DIM / 8 / 256) // 3125
#define NB_PACK 64
#define RS 264  // LDS row stride in bf16 elems: 256 data + 8 pad (16B mult)

typedef __attribute__((ext_vector_type(8))) short short8;
typedef __attribute__((ext_vector_type(16))) float floatx16;

__device__ __forceinline__ unsigned short f2bf(float f) {
    union { float f; unsigned u; } c; c.f = f;
    unsigned u = c.u;
    unsigned r = (u + 0x7FFFu + ((u >> 16) & 1u)) >> 16;
    return (unsigned short)r;
}
__device__ __forceinline__ float bfraw2f(unsigned short b) {
    union { unsigned u; float f; } c; c.u = ((unsigned)b) << 16;
    return c.f;
}
__device__ __forceinline__ float bflo(unsigned u) {
    union { unsigned u; float f; } c; c.u = u << 16; return c.f;
}
__device__ __forceinline__ float bfhi(unsigned u) {
    union { unsigned u; float f; } c; c.u = u & 0xFFFF0000u; return c.f;
}

// ---------------- zero deg+fill (adjacent) and pooled ----------------
__global__ void zero2(int* a, int na, int* b, int nb) {
    int i = blockIdx.x * blockDim.x + threadIdx.x;
    if (i < na) a[i] = 0;
    else if (i < na + nb) b[i - na] = 0;
}

// ---------------- merged: convert_x | pack_w | count_deg (grid-partitioned) ----
__global__ void preprocess(const float4* __restrict__ x, uint4* __restrict__ xb,
                           const float* __restrict__ Wl, const float* __restrict__ Wr,
                           ushort* __restrict__ wpk,
                           const int* __restrict__ edst, int* __restrict__ deg) {
    int b = blockIdx.x;
    if (b < NC_CONV) {
        int i = b * 256 + threadIdx.x;  // chunk of 8 floats
        float4 a = x[i * 2], c = x[i * 2 + 1];
        uint4 o;
        o.x = ((unsigned)f2bf(a.y) << 16) | f2bf(a.x);
        o.y = ((unsigned)f2bf(a.w) << 16) | f2bf(a.z);
        o.z = ((unsigned)f2bf(c.y) << 16) | f2bf(c.x);
        o.w = ((unsigned)f2bf(c.w) << 16) | f2bf(c.z);
        xb[i] = o;
    } else if (b < NC_CONV + NB_PACK) {
        // pack weights into MFMA B-fragment order.
        // u = ((layer*2+m)*8+s)*4+t ; lane l holds B[s*16+(l>>5)*8+j][t*32+(l&31)]
        int u = (b - NC_CONV) * 4 + (threadIdx.x >> 6);
        int l = threadIdx.x & 63;
        int layer = u >> 6, m = (u >> 5) & 1, s = (u >> 2) & 7, tt = u & 3;
        const float* W = ((m == 0) ? Wl : Wr) + (size_t)layer * DIM * DIM;
        int n = tt * 32 + (l & 31);
        int kb = s * 16 + (l >> 5) * 8;
        size_t off = ((size_t)u * 64 + l) * 8;
        for (int j = 0; j < 8; j++)
            wpk[off + j] = f2bf(W[n * DIM + kb + j]);
    } else {
        int e = (b - NC_CONV - NB_PACK) * 256 + threadIdx.x;
        if (e < N_EDGES) atomicAdd(&deg[edst[e]], 1);
    }
}

// ---------------- 3-pass exclusive scan of deg -> rp ----------------
__global__ void scan_pass1(const int* __restrict__ deg, int* __restrict__ bsum) {
    int i = blockIdx.x * 256 + threadIdx.x;
    int v = (i < N_NODES) ? deg[i] : 0;
    for (int off = 32; off > 0; off >>= 1) v += __shfl_down(v, off, 64);
    __shared__ int ws[4];
    int lane = threadIdx.x & 63, w = threadIdx.x >> 6;
    if (lane == 0) ws[w] = v;
    __syncthreads();
    if (threadIdx.x == 0) bsum[blockIdx.x] = ws[0] + ws[1] + ws[2] + ws[3];
}

__global__ void scan_pass2(int* __restrict__ bsum) {
    __shared__ int sm[256];
    int t = threadIdx.x;
    int v = (t < NB_SCAN) ? bsum[t] : 0;
    sm[t] = v;
    __syncthreads();
    for (int off = 1; off < 256; off <<= 1) {
        int u = (t >= off) ? sm[t - off] : 0;
        __syncthreads();
        sm[t] += u;
        __syncthreads();
    }
    if (t < NB_SCAN) bsum[t] = sm[t] - v;
}

__global__ void scan_pass3(const int* __restrict__ deg, const int* __restrict__ bsum,
                           int* __restrict__ rp) {
    int i = blockIdx.x * 256 + threadIdx.x;
    int v = (i < N_NODES) ? deg[i] : 0;
    int lane = threadIdx.x & 63, w = threadIdx.x >> 6;
    int s = v;
    for (int off = 1; off < 64; off <<= 1) {
        int t = __shfl_up(s, off, 64);
        if (lane >= off) s += t;
    }
    __shared__ int ws[4];
    if (lane == 63) ws[w] = s;
    __syncthreads();
    int wo = 0;
    for (int k = 0; k < 4; k++) wo += (k < w) ? ws[k] : 0;
    int incl = s + wo + bsum[blockIdx.x];
    if (i < N_NODES) rp[i + 1] = incl;
    if (i == 0) rp[0] = 0;
}

// ---------------- merged: fill_csr | graph_start ----------------
__global__ void fill_gstart(const int* __restrict__ src, const int* __restrict__ dst,
                            const int* __restrict__ rp, int* __restrict__ fill,
                            int* __restrict__ csr,
                            const int* __restrict__ batch, int* __restrict__ gstart) {
    int b = blockIdx.x;
    if (b < NB_CNT) {
        int e = b * 256 + threadIdx.x;
        if (e >= N_EDGES) return;
        int d = dst[e];
        int pos = atomicAdd(&fill[d], 1);
        csr[rp[d] + pos] = src[e];
    } else {
        int i = (b - NB_CNT) * 256 + threadIdx.x;
        if (i >= N_NODES) return;
        int g0 = batch[i];
        if (i == 0) {
            for (int g = 0; g <= g0; g++) gstart[g] = 0;
        } else {
            int p = batch[i - 1];
            for (int g = p + 1; g <= g0; g++) gstart[g] = i;
        }
        if (i == N_NODES - 1) {
            for (int g = g0 + 1; g <= N_GRAPHS; g++) gstart[g] = N_NODES;
        }
    }
}

// ---------------- aggregation: wave per node, dwordx4 gather (at the edge-gather
// service-rate wall: time invariant to request width/count across r5/r8/r11) -----
__global__ __launch_bounds__(256) void agg_mean_wave4(const uint4* __restrict__ x16B,
                                                      const int* __restrict__ rp,
                                                      const int* __restrict__ csr,
                                                      uint4* __restrict__ agg16B) {
    int wv = threadIdx.x >> 6, lane = threadIdx.x & 63;
    int node = blockIdx.x * 4 + wv;
    if (node >= N_NODES) return;
    int s = rp[node], e = rp[node + 1];
    int ll = lane & 15, eg = lane >> 4;
    float a0 = 0.f, a1 = 0.f, a2 = 0.f, a3 = 0.f, a4 = 0.f, a5 = 0.f, a6 = 0.f, a7 = 0.f;
    for (int base = s; base < e; base += 64) {
        int cnt = min(64, e - base);
        unsigned myidx = (base + lane < e) ? (unsigned)csr[base + lane] : 0u;
        for (int j = 0; j < cnt; j += 16) {
            uint4 v[4];
#pragma unroll
            for (int k = 0; k < 4; k++) {
                int sel = j + k * 4 + eg;
                unsigned idx = __shfl(myidx, sel, 64);
                v[k] = make_uint4(0u, 0u, 0u, 0u);
                if (sel < cnt) v[k] = x16B[(size_t)idx * 16 + ll];
            }
#pragma unroll
            for (int k = 0; k < 4; k++) {
                a0 += bflo(v[k].x); a1 += bfhi(v[k].x);
                a2 += bflo(v[k].y); a3 += bfhi(v[k].y);
                a4 += bflo(v[k].z); a5 += bfhi(v[k].z);
                a6 += bflo(v[k].w); a7 += bfhi(v[k].w);
            }
        }
    }
    a0 += __shfl_xor(a0, 16, 64); a0 += __shfl_xor(a0, 32, 64);
    a1 += __shfl_xor(a1, 16, 64); a1 += __shfl_xor(a1, 32, 64);
    a2 += __shfl_xor(a2, 16, 64); a2 += __shfl_xor(a2, 32, 64);
    a3 += __shfl_xor(a3, 16, 64); a3 += __shfl_xor(a3, 32, 64);
    a4 += __shfl_xor(a4, 16, 64); a4 += __shfl_xor(a4, 32, 64);
    a5 += __shfl_xor(a5, 16, 64); a5 += __shfl_xor(a5, 32, 64);
    a6 += __shfl_xor(a6, 16, 64); a6 += __shfl_xor(a6, 32, 64);
    a7 += __shfl_xor(a7, 16, 64); a7 += __shfl_xor(a7, 32, 64);
    if (eg == 0) {
        float inv = 1.0f / (float)max(e - s, 1);
        uint4 o;
        o.x = ((unsigned)f2bf(a1 * inv) << 16) | f2bf(a0 * inv);
        o.y = ((unsigned)f2bf(a3 * inv) << 16) | f2bf(a2 * inv);
        o.z = ((unsigned)f2bf(a5 * inv) << 16) | f2bf(a4 * inv);
        o.w = ((unsigned)f2bf(a7 * inv) << 16) | f2bf(a6 * inv);
        agg16B[(size_t)node * 16 + ll] = o;
    }
}

// ---------------- fused dual-GEMM layer, MFMA bf16, 64-node blocks ----------------
// 33.8 KB LDS -> 4 blocks/CU (16 waves). wave w: m-tile (w>>1), output half (w&1).
__global__ __launch_bounds__(256, 4) void fused_layer_mfma(const ushort* __restrict__ agg,
                                                           const ushort* __restrict__ xin,
                                                           ushort* __restrict__ xout,
                                                           const ushort* __restrict__ wpk,
                                                           const float* __restrict__ bias,
                                                           int residual) {
    __shared__ ushort sA[64 * RS];  // row r: [agg(128) | x(128) | pad(8)]
    int t = threadIdx.x;
    int node0 = blockIdx.x * 64;

    const uint4* aggv = (const uint4*)(agg + (size_t)node0 * DIM);
    const uint4* xv   = (const uint4*)(xin + (size_t)node0 * DIM);
    for (int i = t; i < 64 * 32; i += 256) {
        int r = i >> 5, c = i & 31;
        uint4 val = make_uint4(0u, 0u, 0u, 0u);
        if (node0 + r < N_NODES)
            val = (c < 16) ? aggv[r * 16 + c] : xv[r * 16 + (c - 16)];
        *(uint4*)&sA[r * RS + c * 8] = val;
    }
    __syncthreads();

    int w = t >> 6, l = t & 63;
    int m0 = (w >> 1) * 32;
    int th = w & 1;  // output half: t4 in {2*th, 2*th+1}
    const ushort* arow = &sA[(m0 + (l & 31)) * RS];
    int khalf = (l >> 5) * 8;

    floatx16 acc0, acc1;
    for (int ii = 0; ii < 16; ii++) acc0[ii] = acc1[ii] = 0.f;

    const ushort* wl8 = wpk + (size_t)l * 8 + (size_t)(2 * th) * 512;
#pragma unroll
    for (int s2 = 0; s2 < 16; s2++) {
        int m = s2 >> 3, s = s2 & 7;
        short8 a = *(const short8*)(arow + m * 128 + s * 16 + khalf);
        size_t fb = (size_t)((m * 8 + s) * 4) * 512;
        short8 b0 = *(const short8*)(wl8 + fb);
        short8 b1 = *(const short8*)(wl8 + fb + 512);
        acc0 = __builtin_amdgcn_mfma_f32_32x32x16_bf16(a, b0, acc0, 0, 0, 0);
        acc1 = __builtin_amdgcn_mfma_f32_32x32x16_bf16(a, b1, acc1, 0, 0, 0);
    }

    int col = l & 31;
    int rbase = 4 * (l >> 5);
    floatx16 accs[2] = {acc0, acc1};
    for (int ti = 0; ti < 2; ti++) {
        int n = (2 * th + ti) * 32 + col;
        float bv = bias[n];
#pragma unroll
        for (int r = 0; r < 16; r++) {
            int row = (r & 3) + 8 * (r >> 2) + rbase;
            int gm = m0 + row;
            int gn = node0 + gm;
            if (gn >= N_NODES) continue;
            float v = accs[ti][r] + bv;
            v = (v >= 0.f) ? v : NEG_SLOPE * v;
            if (residual) v += bfraw2f(sA[gm * RS + 128 + n]);
            xout[(size_t)gn * DIM + n] = f2bf(v);
        }
    }
}

// ---------------- global mean pool, parallel segment-sum ----------------
__global__ __launch_bounds__(128) void pool_partial(const ushort* __restrict__ xb,
                                                    const int* __restrict__ batch,
                                                    float* __restrict__ pooled) {
    int nb = blockIdx.x * 128;
    int ne = min(nb + 128, N_NODES);
    int d = threadIdx.x;
    int gcur = batch[nb];
    float acc = 0.f;
    for (int n = nb; n < ne; n++) {
        int g = batch[n];
        if (g != gcur) {
            atomicAdd(&pooled[gcur * DIM + d], acc);
            acc = 0.f;
            gcur = g;
        }
        acc += bfraw2f(xb[(size_t)n * DIM + d]);
    }
    atomicAdd(&pooled[gcur * DIM + d], acc);
}

__global__ void pool_final(const float* __restrict__ pooled,
                           const int* __restrict__ gstart,
                           float* __restrict__ out) {
    int i = blockIdx.x * blockDim.x + threadIdx.x;
    if (i >= N_GRAPHS * DIM) return;
    int g = i >> 7;
    int cnt = gstart[g + 1] - gstart[g];
    out[i] = pooled[i] / (float)max(cnt, 1);
}

// ---------------- launch ----------------

extern "C" void kernel_launch(void* const* d_in, const int* in_sizes, int n_in,
                              void* d_out, int out_size, void* d_ws, size_t ws_size,
                              hipStream_t stream) {
    const float* x     = (const float*)d_in[0];
    const int*   ei    = (const int*)d_in[1];
    const int*   batch = (const int*)d_in[2];
    const float* Wl    = (const float*)d_in[3];
    const float* bl    = (const float*)d_in[4];
    const float* Wr    = (const float*)d_in[5];
    float* out = (float*)d_out;

    const int* esrc = ei;
    const int* edst = ei + N_EDGES;

    // workspace layout
    ushort* xb0  = (ushort*)d_ws;                         // [N,128] bf16
    ushort* xbuf = xb0 + (size_t)N_NODES * DIM;           // [N,128] bf16
    ushort* agg  = xbuf + (size_t)N_NODES * DIM;          // [N,128] bf16
    ushort* wpk  = agg + (size_t)N_NODES * DIM;           // [4][2][128*128] bf16
    int* deg    = (int*)(wpk + (size_t)N_LAYERS * 2 * DIM * DIM);
    int* fill   = deg + N_NODES;
    int* csr    = fill + N_NODES;
    int* rp     = csr + N_EDGES;
    int* gstart = rp + (N_NODES + 1);
    int* bsum   = gstart + (N_GRAPHS + 1);
    float* pooled = (float*)(bsum + NB_SCAN);             // [G,128] fp32

    // 1. zero deg+fill (adjacent, 2N) and pooled (G*D)
    zero2<<<(2 * N_NODES + N_GRAPHS * DIM + 255) / 256, 256, 0, stream>>>(
        deg, 2 * N_NODES, (int*)pooled, N_GRAPHS * DIM);

    // 2. convert | pack | count (one grid)
    preprocess<<<NC_CONV + NB_PACK + NB_CNT, 256, 0, stream>>>(
        (const float4*)x, (uint4*)xb0, Wl, Wr, wpk, edst, deg);

    // 3. scan
    scan_pass1<<<NB_SCAN, 256, 0, stream>>>(deg, bsum);
    scan_pass2<<<1, 256, 0, stream>>>(bsum);
    scan_pass3<<<NB_SCAN, 256, 0, stream>>>(deg, bsum, rp);

    // 4. fill csr | graph segment starts
    fill_gstart<<<NB_CNT + NB_SCAN, 256, 0, stream>>>(esrc, edst, rp, fill, csr,
                                                      batch, gstart);

    // 5. layers
    int agg_blocks = (N_NODES + 3) / 4;
    int gemm_blocks = (N_NODES + 63) / 64;
    for (int l = 0; l < N_LAYERS; l++) {
        const ushort* xin = (l == 0) ? xb0 : xbuf;
        agg_mean_wave4<<<agg_blocks, 256, 0, stream>>>((const uint4*)xin, rp, csr, (uint4*)agg);
        fused_layer_mfma<<<gemm_blocks, 256, 0, stream>>>(
            agg, xin, xbuf, wpk + (size_t)l * 2 * DIM * DIM,
            bl + (size_t)l * DIM, (l >= 2) ? 1 : 0);
    }

    // 6. pool
    pool_partial<<<(N_NODES + 127) / 128, 128, 0, stream>>>(xbuf, batch, pooled);
    pool_final<<<(N_GRAPHS * DIM + 255) / 256, 256, 0, stream>>>(pooled, gstart, out);
}